// Round 12
// baseline (838.095 us; speedup 1.0000x reference)
//
#include <hip/hip_runtime.h>
#include <hip/hip_bf16.h>
#include <hip/hip_fp16.h>

// tanh-RNN + FC on MI355X.
// conv_w -> gemm_xproj (f16 MFMA, scan-native xp layout) -> rnn_scan11
// (32 blocks x 512 thr, 2 waves/SIMD; FULL W_hh in AGPRs: 8 waves x 64
// "+a"-pinned B-frags = 256 AGPR/wave; h double-buffered in LDS -> ONE
// barrier/step; xp prefetched a full step ahead; hoisted store pointers)
// -> gemm_logits (in-place over d_out).

typedef _Float16 half8 __attribute__((ext_vector_type(8)));
typedef _Float16 half4 __attribute__((ext_vector_type(4)));
typedef float f32x4 __attribute__((ext_vector_type(4)));

// ws layout (bytes)
#define XPW_OFF   0UL            // 64MB x_proj f16 (scan-native layout)
#define WIH_OFF   67108864UL     // 512KB f16 W_ih
#define FCW_OFF   67633152UL     // 256KB f16 fc_w
#define BIAS_OFF  67895296UL     // 2KB f32 bias2
#define WRESA_OFF 67897344UL     // 512KB W_hh B-frags [w(8)][nt(4)][s(16)][lane(64)][8]

// column stripe ntg = nt*8 + w (nt=0..3), col = ntg*16 + (frag lane&15).

// ---------------------------------------------------------------------------
// conv_w: f16 W_ih, fc_w; bias2 = b_ih + b_hh; W_hh -> B-frag layout.
// B-frag value: lane l, frag (ntg,s), elem i = Whh[ntg*16+(l&15)][s*32+(l>>4)*8+i]
// wresA element index = ((w*4 + nt)*16 + s)*512 + l*8 + i, ntg = nt*8+w.
// ---------------------------------------------------------------------------
__global__ void conv_w(const float* __restrict__ Wih, const float* __restrict__ Whh,
                       const float* __restrict__ fcw, const float* __restrict__ bih,
                       const float* __restrict__ bhh,
                       _Float16* __restrict__ wih_h, _Float16* __restrict__ fcw_h,
                       float* __restrict__ bias2, _Float16* __restrict__ wresA) {
    int idx = blockIdx.x * 256 + threadIdx.x;
    if (idx < 262144) {
        wih_h[idx] = (_Float16)Wih[idx];
        // wresA: [w(8)][nt(4)][s(16)][lane(64)][8]
        const int i = idx & 7, l = (idx >> 3) & 63, s = (idx >> 9) & 15;
        const int nt = (idx >> 13) & 3, w = idx >> 15;
        const int ntg = nt * 8 + w;
        wresA[idx] = (_Float16)Whh[(size_t)(ntg * 16 + (l & 15)) * 512 + s * 32 + (l >> 4) * 8 + i];
    }
    if (idx < 131072) fcw_h[idx] = (_Float16)fcw[idx];
    if (idx < 512) bias2[idx] = bih[idx] + bhh[idx];
}

// ---------------------------------------------------------------------------
// K1: x_proj = states @ W_ih^T + bias2, scan-native output (same as R11):
//   dst = (bg*128+t)*8192 + (w_s*64 + kgs*16 + ln)*16 + qs*4 + nt
//   where b = bg*16 + kgs*4 + qs, col = (nt*8 + w_s)*16 + ln.
// ---------------------------------------------------------------------------
__global__ __launch_bounds__(256) void gemm_xproj(const float* __restrict__ A,
                                                  const _Float16* __restrict__ Bw,
                                                  const float* __restrict__ bias2,
                                                  _Float16* __restrict__ out) {
    __shared__ _Float16 As[128 * 32];
    __shared__ _Float16 Bs[64 * 32];
    const int tid = threadIdx.x;
    const int s_ = blockIdx.x;
    const int z = s_ & 7, k_ = s_ >> 3;
    const int gid = z * 512 + k_;
    const int b = gid >> 3;              // batch
    const int wsp = gid & 7;             // stripe group w_s
    const int lane = tid & 63, w1 = tid >> 6;
    const int ln = lane & 15, kg = lane >> 4;

    f32x4 acc[2][4];
#pragma unroll
    for (int m = 0; m < 2; m++)
#pragma unroll
        for (int n = 0; n < 4; n++) acc[m][n] = (f32x4)0.0f;

    const int sr = tid >> 1, sc = (tid & 1) * 16;      // A staging: 128 x 32
    const int sr2 = tid >> 2, sc2 = (tid & 3) * 8;     // B staging: 64 x 32
    const int brow = (sr2 >> 4) * 128 + wsp * 16 + (sr2 & 15);

    for (int k0 = 0; k0 < 512; k0 += 32) {
        {
            const float* ga = A + (size_t)(b * 128 + sr) * 512 + k0 + sc;
            float4 f0 = *(const float4*)(ga + 0);
            float4 f1 = *(const float4*)(ga + 4);
            float4 f2 = *(const float4*)(ga + 8);
            float4 f3 = *(const float4*)(ga + 12);
            half8 h0, h1;
            h0[0] = (_Float16)f0.x; h0[1] = (_Float16)f0.y; h0[2] = (_Float16)f0.z; h0[3] = (_Float16)f0.w;
            h0[4] = (_Float16)f1.x; h0[5] = (_Float16)f1.y; h0[6] = (_Float16)f1.z; h0[7] = (_Float16)f1.w;
            h1[0] = (_Float16)f2.x; h1[1] = (_Float16)f2.y; h1[2] = (_Float16)f2.z; h1[3] = (_Float16)f2.w;
            h1[4] = (_Float16)f3.x; h1[5] = (_Float16)f3.y; h1[6] = (_Float16)f3.z; h1[7] = (_Float16)f3.w;
            *(half8*)&As[sr * 32 + sc] = h0;
            *(half8*)&As[sr * 32 + sc + 8] = h1;
        }
        *(half8*)&Bs[sr2 * 32 + sc2] = *(const half8*)(Bw + (size_t)brow * 512 + k0 + sc2);
        __syncthreads();
        half8 af[2], bf[4];
#pragma unroll
        for (int m = 0; m < 2; m++) af[m] = *(const half8*)&As[(w1 * 32 + m * 16 + ln) * 32 + kg * 8];
#pragma unroll
        for (int n = 0; n < 4; n++) bf[n] = *(const half8*)&Bs[(n * 16 + ln) * 32 + kg * 8];
#pragma unroll
        for (int m = 0; m < 2; m++)
#pragma unroll
            for (int n = 0; n < 4; n++)
                acc[m][n] = __builtin_amdgcn_mfma_f32_16x16x32_f16(af[m], bf[n], acc[m][n], 0, 0, 0);
        __syncthreads();
    }
    // epilogue: 8 half4 stores into scan-native layout
    const int bg = b >> 4, kgs = (b >> 2) & 3, qs = b & 3;
    float bv[4];
#pragma unroll
    for (int n = 0; n < 4; n++) bv[n] = bias2[(n * 8 + wsp) * 16 + ln];
    const size_t tb = (size_t)(bg * 128) * 8192 + (size_t)(wsp * 64 + kgs * 16 + ln) * 16 + qs * 4;
#pragma unroll
    for (int m = 0; m < 2; m++)
#pragma unroll
        for (int q = 0; q < 4; q++) {
            half4 v;
#pragma unroll
            for (int n = 0; n < 4; n++) v[n] = (_Float16)(acc[m][n][q] + bv[n]);
            const int t = w1 * 32 + m * 16 + kg * 4 + q;
            *(half4*)&out[tb + (size_t)t * 8192] = v;
        }
}

// ---------------------------------------------------------------------------
// Scan v11: 32 blocks x 512 thr (8 waves, 2/SIMD). Wave w owns stripes
// ntg {w, 8+w, 16+w, 24+w} = 64 B-frags in 256 AGPRs ("+a"-pinned).
// h double-buffered in LDS (k8-major, 2 x 16KB): step t reads hb[t&1],
// writes hb[(t+1)&1] -> ONE barrier per step. xp prefetched one step ahead.
// rnn stores after the barrier via 4 hoisted row pointers.
// ---------------------------------------------------------------------------
__global__ __launch_bounds__(512, 2) void rnn_scan11(
    const _Float16* __restrict__ xps,     // scan-native x_proj
    const _Float16* __restrict__ wresA,   // AGPR B-frags
    const int* __restrict__ term,         // [512][128] int32
    const float* __restrict__ h0,         // [512][512] f32
    float* dout) {
    __shared__ __align__(16) _Float16 hb[16384];     // h, k8-major, double-buffered
    __shared__ unsigned int term_lds[16][4];
    const int tid = threadIdx.x;
    const int bg = blockIdx.x;
    const int R0 = bg * 16;
    const int lane = tid & 63, w = tid >> 6;
    const int ln = lane & 15, kg = lane >> 4;
    _Float16* rnn = (_Float16*)dout;

    // ---- 64 B-frags -> 256 AGPRs; per-wave stride 64*512 = 32768 ----
    half8 wf[64];
    {
        const _Float16* wp = wresA + (size_t)w * 32768 + lane * 8;
#pragma unroll
        for (int f = 0; f < 64; f++) wf[f] = *(const half8*)(wp + (size_t)f * 512);
    }
#pragma unroll
    for (int f = 0; f < 64; f++) asm volatile("" : "+a"(wf[f]));

    // ---- h0 -> hb buffer 0 (f32 -> f16, k8-major) ----
    {
        const int r = tid >> 5, c0 = (tid & 31) * 16;
        const float* gh = h0 + (size_t)(R0 + r) * 512 + c0;
        half8 v0, v1;
#pragma unroll
        for (int i = 0; i < 8; i++) { v0[i] = (_Float16)gh[i]; v1[i] = (_Float16)gh[8 + i]; }
        const int kb = c0 >> 3;
        *(half8*)&hb[kb * 128 + r * 8] = v0;
        *(half8*)&hb[(kb + 1) * 128 + r * 8] = v1;
    }
    // ---- termination bitmasks ----
    if (tid < 64) {
        const int r = tid >> 2, word = tid & 3;
        unsigned int m = 0;
        for (int b2 = 0; b2 < 32; b2++)
            m |= (term[(R0 + r) * 128 + word * 32 + b2] ? 1u : 0u) << b2;
        term_lds[r][word] = m;
    }
    __syncthreads();

    // hoisted addresses
    const int abase = kg * 128 + ln * 8;                              // a-frag LDS base (halfs)
    const int hbase = (w * 2 + (ln >> 3)) * 128 + kg * 32 + (ln & 7); // h-write LDS base (halfs)
    const _Float16* xbase = xps + (size_t)(bg * 128) * 8192 + tid * 16;
    _Float16* rp0 = rnn + (size_t)(R0 + kg * 4 + 0) * 128 * 512 + w * 16 + ln;
    _Float16* rp1 = rp0 + (size_t)128 * 512;
    _Float16* rp2 = rp1 + (size_t)128 * 512;
    _Float16* rp3 = rp2 + (size_t)128 * 512;

    half8 xc0 = *(const half8*)(xbase);        // xp(t=0)
    half8 xc1 = *(const half8*)(xbase + 8);
    unsigned int tmask[4];

#pragma unroll 1
    for (int t = 0; t < 128; ++t) {
        if ((t & 31) == 0) {
#pragma unroll
            for (int q = 0; q < 4; q++) tmask[q] = term_lds[kg * 4 + q][t >> 5];
        }
        // prefetch xp(t+1) — a full step of latency cover
        const int tn = (t < 127) ? (t + 1) : 127;
        const _Float16* xnp = xbase + (size_t)tn * 8192;
        const half8 xn0 = *(const half8*)(xnp);
        const half8 xn1 = *(const half8*)(xnp + 8);

        const _Float16* hr = hb + (t & 1) * 8192;      // read buffer: h(t)
        _Float16* hw = hb + ((t & 1) ^ 1) * 8192;      // write buffer: h(t+1)

        f32x4 acc[4];
#pragma unroll
        for (int n = 0; n < 4; n++) acc[n] = (f32x4)0.0f;

#pragma unroll
        for (int s = 0; s < 16; s++) {
            const half8 a = *(const half8*)&hr[abase + s * 512];
            acc[0] = __builtin_amdgcn_mfma_f32_16x16x32_f16(a, wf[s],      acc[0], 0, 0, 0);
            acc[1] = __builtin_amdgcn_mfma_f32_16x16x32_f16(a, wf[16 + s], acc[1], 0, 0, 0);
            acc[2] = __builtin_amdgcn_mfma_f32_16x16x32_f16(a, wf[32 + s], acc[2], 0, 0, 0);
            acc[3] = __builtin_amdgcn_mfma_f32_16x16x32_f16(a, wf[48 + s], acc[3], 0, 0, 0);
        }

        // tanh; masked h(t+1) -> hw (other buffer: no barrier needed first)
        _Float16 hh[16];
#pragma unroll
        for (int q = 0; q < 4; q++) {
            const bool dead = (tmask[q] >> (t & 31)) & 1;
#pragma unroll
            for (int nt = 0; nt < 4; nt++) {
                const int u = q * 4 + nt;
                const float xval = (float)(u < 8 ? xc0[u] : xc1[u - 8]);
                const float pre = acc[nt][q] + xval;
                const float e = __expf(2.0f * pre);
                const float hn = 1.0f - 2.0f * __builtin_amdgcn_rcpf(e + 1.0f);
                hh[q * 4 + nt] = (_Float16)hn;
                hw[hbase + nt * 2048 + q * 8] = dead ? (_Float16)0.0f : hh[q * 4 + nt];
            }
        }
        __syncthreads();   // the ONLY barrier: h(t+1) complete, h(t) reads done

        // rnn_out stores after barrier: drain overlaps next step's MFMA phase
        rp0[0] = hh[0]; rp0[128] = hh[1]; rp0[256] = hh[2]; rp0[384] = hh[3];
        rp1[0] = hh[4]; rp1[128] = hh[5]; rp1[256] = hh[6]; rp1[384] = hh[7];
        rp2[0] = hh[8]; rp2[128] = hh[9]; rp2[256] = hh[10]; rp2[384] = hh[11];
        rp3[0] = hh[12]; rp3[128] = hh[13]; rp3[256] = hh[14]; rp3[384] = hh[15];
        rp0 += 512; rp1 += 512; rp2 += 512; rp3 += 512;

        xc0 = xn0; xc1 = xn1;
    }

    // ---- h_final (masked h(128), lives in buffer 0) -> f32 at d_out + 65536*256 ----
    {
        const int r = tid >> 5, c0 = (tid & 31) * 16;
        const int kb = c0 >> 3;
        half8 v0 = *(const half8*)&hb[kb * 128 + r * 8];
        half8 v1 = *(const half8*)&hb[(kb + 1) * 128 + r * 8];
        float* gf = dout + (size_t)65536 * 256 + (size_t)(R0 + r) * 512 + c0;
#pragma unroll
        for (int i = 0; i < 8; i++) { gf[i] = (float)v0[i]; gf[8 + i] = (float)v1[i]; }
    }
}

// ---------------------------------------------------------------------------
// K3: logits[65536,256] (f32) = rnn_out(f16, in d_out) @ fc_w^T + fc_b
// ---------------------------------------------------------------------------
__global__ __launch_bounds__(512) void gemm_logits(const _Float16* Arnn,
                                                   const _Float16* __restrict__ Bw,
                                                   const float* __restrict__ biasv,
                                                   float* out) {
    __shared__ _Float16 As[128 * 32];
    __shared__ _Float16 Bs[256 * 32];
    const int tid = threadIdx.x;
    const int m0 = blockIdx.x * 128;
    const int lane = tid & 63, w = tid >> 6;
    const int wr = (w >> 2) * 64, wc = (w & 3) * 64;
    const int ln = lane & 15, kg = lane >> 4;

    f32x4 acc[4][4];
#pragma unroll
    for (int m = 0; m < 4; m++)
#pragma unroll
        for (int n = 0; n < 4; n++) acc[m][n] = (f32x4)0.0f;

    const int ar = tid >> 2, ac = (tid & 3) * 8;
    const int br = tid >> 1, bc = (tid & 1) * 16;

    for (int k0 = 0; k0 < 512; k0 += 32) {
        *(half8*)&As[ar * 32 + ac] = *(const half8*)(Arnn + (size_t)(m0 + ar) * 512 + k0 + ac);
        {
            const _Float16* gb = Bw + (size_t)br * 512 + k0 + bc;
            *(half8*)&Bs[br * 32 + bc] = *(const half8*)(gb);
            *(half8*)&Bs[br * 32 + bc + 8] = *(const half8*)(gb + 8);
        }
        __syncthreads();
        half8 af[4], bf[4];
#pragma unroll
        for (int m = 0; m < 4; m++) af[m] = *(const half8*)&As[(wr + m * 16 + ln) * 32 + kg * 8];
#pragma unroll
        for (int n = 0; n < 4; n++) bf[n] = *(const half8*)&Bs[(wc + n * 16 + ln) * 32 + kg * 8];
#pragma unroll
        for (int m = 0; m < 4; m++)
#pragma unroll
            for (int n = 0; n < 4; n++)
                acc[m][n] = __builtin_amdgcn_mfma_f32_16x16x32_f16(af[m], bf[n], acc[m][n], 0, 0, 0);
        __syncthreads();
    }
#pragma unroll
    for (int m = 0; m < 4; m++)
#pragma unroll
        for (int n = 0; n < 4; n++) {
            const int col = wc + n * 16 + ln;
            const float bv = biasv[col];
#pragma unroll
            for (int q = 0; q < 4; q++) {
                const int row = m0 + wr + m * 16 + kg * 4 + q;
                out[(size_t)row * 256 + col] = acc[m][n][q] + bv;
            }
        }
}

// ---------------------------------------------------------------------------
extern "C" void kernel_launch(void* const* d_in, const int* in_sizes, int n_in,
                              void* d_out, int out_size, void* d_ws, size_t ws_size,
                              hipStream_t stream) {
    const float* states = (const float*)d_in[0];
    const int*   term   = (const int*)d_in[1];
    const float* h0     = (const float*)d_in[2];
    const float* Wih    = (const float*)d_in[3];
    const float* Whh    = (const float*)d_in[4];
    const float* bih    = (const float*)d_in[5];
    const float* bhh    = (const float*)d_in[6];
    const float* fcw    = (const float*)d_in[7];
    const float* fcb    = (const float*)d_in[8];

    char* ws = (char*)d_ws;
    _Float16* xpw   = (_Float16*)(ws + XPW_OFF);
    _Float16* wih_h = (_Float16*)(ws + WIH_OFF);
    _Float16* fcw_h = (_Float16*)(ws + FCW_OFF);
    float*    bias2 = (float*)(ws + BIAS_OFF);
    _Float16* wresA = (_Float16*)(ws + WRESA_OFF);

    conv_w<<<1024, 256, 0, stream>>>(Wih, Whh, fcw, bih, bhh, wih_h, fcw_h, bias2, wresA);
    gemm_xproj<<<4096, 256, 0, stream>>>(states, wih_h, bias2, xpw);
    rnn_scan11<<<32, 512, 0, stream>>>(xpw, wresA, term, h0, (float*)d_out);
    gemm_logits<<<512, 512, 0, stream>>>((const _Float16*)d_out, fcw_h, fcb, (float*)d_out);
}

// Round 13
// 575.933 us; speedup vs baseline: 1.4552x; 1.4552x over previous
//
#include <hip/hip_runtime.h>
#include <hip/hip_bf16.h>
#include <hip/hip_fp16.h>

// tanh-RNN + FC on MI355X.
// conv_w -> gemm_xproj (f16 MFMA, scan-native xp layout) -> rnn_scan12
// (32 blocks x 512 thr; W_hh resident: 384KB AGPR (8 waves x 48 "+a"-pinned
// B-frags) + 128KB LDS tile; h DOUBLE-BUFFERED in LDS -> ONE barrier/step;
// term masks in registers; xp prefetched a step ahead; hoisted store ptrs)
// -> gemm_logits (in-place over d_out).

typedef _Float16 half8 __attribute__((ext_vector_type(8)));
typedef _Float16 half4 __attribute__((ext_vector_type(4)));
typedef float f32x4 __attribute__((ext_vector_type(4)));

// ws layout (bytes)
#define XPW_OFF   0UL            // 64MB x_proj f16 (scan-native layout)
#define WIH_OFF   67108864UL     // 512KB f16 W_ih
#define FCW_OFF   67633152UL     // 256KB f16 fc_w
#define BIAS_OFF  67895296UL     // 2KB f32 bias2
#define WRESA_OFF 67897344UL     // 384KB AGPR W frags [w(8)][nt(3)][s(16)][lane(64)][8]
#define WRESL_OFF 68290560UL     // 128KB LDS  W frags [w(8)][s(16)][lane(64)][8]

// column stripe ntg = nt*8 + w (nt=0..2 AGPR) or 24+w (LDS); col = ntg*16 + ln.

// ---------------------------------------------------------------------------
// conv_w: f16 W_ih, fc_w; bias2 = b_ih + b_hh; W_hh -> B-frag layouts.
// B-frag value: lane l, frag (ntg,s), elem i = Whh[ntg*16+(l&15)][s*32+(l>>4)*8+i]
// ---------------------------------------------------------------------------
__global__ void conv_w(const float* __restrict__ Wih, const float* __restrict__ Whh,
                       const float* __restrict__ fcw, const float* __restrict__ bih,
                       const float* __restrict__ bhh,
                       _Float16* __restrict__ wih_h, _Float16* __restrict__ fcw_h,
                       float* __restrict__ bias2,
                       _Float16* __restrict__ wresA, _Float16* __restrict__ wresL) {
    int idx = blockIdx.x * 256 + threadIdx.x;
    if (idx < 262144) wih_h[idx] = (_Float16)Wih[idx];
    if (idx < 196608) {   // wresA: [w(8)][nt(3)][s(16)][lane][8]
        const int i = idx & 7, l = (idx >> 3) & 63, s = (idx >> 9) & 15;
        const int rest = idx >> 13;              // w*3 + nt, 0..23
        const int w = rest / 3, nt = rest % 3;
        const int ntg = nt * 8 + w;
        wresA[idx] = (_Float16)Whh[(size_t)(ntg * 16 + (l & 15)) * 512 + s * 32 + (l >> 4) * 8 + i];
    }
    if (idx < 65536) {    // wresL: [w(8)][s(16)][lane][8], ntg = 24+w
        const int i = idx & 7, l = (idx >> 3) & 63, s = (idx >> 9) & 15, w = idx >> 13;
        const int ntg = 24 + w;
        wresL[idx] = (_Float16)Whh[(size_t)(ntg * 16 + (l & 15)) * 512 + s * 32 + (l >> 4) * 8 + i];
    }
    if (idx < 131072) fcw_h[idx] = (_Float16)fcw[idx];
    if (idx < 512) bias2[idx] = bih[idx] + bhh[idx];
}

// ---------------------------------------------------------------------------
// K1: x_proj = states @ W_ih^T + bias2, scan-native output:
//   dst = (bg*128+t)*8192 + (w_s*64 + kgs*16 + ln)*16 + qs*4 + nt
//   where b = bg*16 + kgs*4 + qs, col = (nt*8 + w_s)*16 + ln.
// ---------------------------------------------------------------------------
__global__ __launch_bounds__(256) void gemm_xproj(const float* __restrict__ A,
                                                  const _Float16* __restrict__ Bw,
                                                  const float* __restrict__ bias2,
                                                  _Float16* __restrict__ out) {
    __shared__ _Float16 As[128 * 32];
    __shared__ _Float16 Bs[64 * 32];
    const int tid = threadIdx.x;
    const int s_ = blockIdx.x;
    const int z = s_ & 7, k_ = s_ >> 3;
    const int gid = z * 512 + k_;
    const int b = gid >> 3;              // batch
    const int wsp = gid & 7;             // stripe group w_s
    const int lane = tid & 63, w1 = tid >> 6;
    const int ln = lane & 15, kg = lane >> 4;

    f32x4 acc[2][4];
#pragma unroll
    for (int m = 0; m < 2; m++)
#pragma unroll
        for (int n = 0; n < 4; n++) acc[m][n] = (f32x4)0.0f;

    const int sr = tid >> 1, sc = (tid & 1) * 16;      // A staging: 128 x 32
    const int sr2 = tid >> 2, sc2 = (tid & 3) * 8;     // B staging: 64 x 32
    const int brow = (sr2 >> 4) * 128 + wsp * 16 + (sr2 & 15);

    for (int k0 = 0; k0 < 512; k0 += 32) {
        {
            const float* ga = A + (size_t)(b * 128 + sr) * 512 + k0 + sc;
            float4 f0 = *(const float4*)(ga + 0);
            float4 f1 = *(const float4*)(ga + 4);
            float4 f2 = *(const float4*)(ga + 8);
            float4 f3 = *(const float4*)(ga + 12);
            half8 h0, h1;
            h0[0] = (_Float16)f0.x; h0[1] = (_Float16)f0.y; h0[2] = (_Float16)f0.z; h0[3] = (_Float16)f0.w;
            h0[4] = (_Float16)f1.x; h0[5] = (_Float16)f1.y; h0[6] = (_Float16)f1.z; h0[7] = (_Float16)f1.w;
            h1[0] = (_Float16)f2.x; h1[1] = (_Float16)f2.y; h1[2] = (_Float16)f2.z; h1[3] = (_Float16)f2.w;
            h1[4] = (_Float16)f3.x; h1[5] = (_Float16)f3.y; h1[6] = (_Float16)f3.z; h1[7] = (_Float16)f3.w;
            *(half8*)&As[sr * 32 + sc] = h0;
            *(half8*)&As[sr * 32 + sc + 8] = h1;
        }
        *(half8*)&Bs[sr2 * 32 + sc2] = *(const half8*)(Bw + (size_t)brow * 512 + k0 + sc2);
        __syncthreads();
        half8 af[2], bf[4];
#pragma unroll
        for (int m = 0; m < 2; m++) af[m] = *(const half8*)&As[(w1 * 32 + m * 16 + ln) * 32 + kg * 8];
#pragma unroll
        for (int n = 0; n < 4; n++) bf[n] = *(const half8*)&Bs[(n * 16 + ln) * 32 + kg * 8];
#pragma unroll
        for (int m = 0; m < 2; m++)
#pragma unroll
            for (int n = 0; n < 4; n++)
                acc[m][n] = __builtin_amdgcn_mfma_f32_16x16x32_f16(af[m], bf[n], acc[m][n], 0, 0, 0);
        __syncthreads();
    }
    // epilogue: 8 half4 stores into scan-native layout
    const int bg = b >> 4, kgs = (b >> 2) & 3, qs = b & 3;
    float bv[4];
#pragma unroll
    for (int n = 0; n < 4; n++) bv[n] = bias2[(n * 8 + wsp) * 16 + ln];
    const size_t tb = (size_t)(bg * 128) * 8192 + (size_t)(wsp * 64 + kgs * 16 + ln) * 16 + qs * 4;
#pragma unroll
    for (int m = 0; m < 2; m++)
#pragma unroll
        for (int q = 0; q < 4; q++) {
            half4 v;
#pragma unroll
            for (int n = 0; n < 4; n++) v[n] = (_Float16)(acc[m][n][q] + bv[n]);
            const int t = w1 * 32 + m * 16 + kg * 4 + q;
            *(half4*)&out[tb + (size_t)t * 8192] = v;
        }
}

// ---------------------------------------------------------------------------
// Scan v12: 32 blocks x 512 thr (8 waves, 2/SIMD). Wave w owns stripes
// ntg {w, 8+w, 16+w} as 48 AGPR frags (192 regs, "+a"-pinned) + stripe 24+w
// from the 128KB LDS W tile (R11's proven split). h double-buffered in LDS
// (2 x 16KB): step t reads hb[t&1], writes hb[(t&1)^1] -> ONE barrier/step.
// term masks in registers (select chain). LDS = 160KB exactly.
// ---------------------------------------------------------------------------
__global__ __launch_bounds__(512, 2) void rnn_scan12(
    const _Float16* __restrict__ xps,     // scan-native x_proj
    const _Float16* __restrict__ wresA,   // AGPR frags
    const _Float16* __restrict__ wresL,   // LDS frags
    const int* __restrict__ term,         // [512][128] int32
    const float* __restrict__ h0,         // [512][512] f32
    float* dout) {
    __shared__ __align__(16) _Float16 hb[16384];     // h, k8-major, double-buffered (32KB)
    __shared__ __align__(16) _Float16 wl[65536];     // W stripes ntg 24..31 (128KB)
    const int tid = threadIdx.x;
    const int bg = blockIdx.x;
    const int R0 = bg * 16;
    const int lane = tid & 63, w = tid >> 6;
    const int ln = lane & 15, kg = lane >> 4;
    _Float16* rnn = (_Float16*)dout;

    // ---- 48 AGPR frags (192 AGPRs); per-wave stride 48*512 = 24576 ----
    half8 wf[48];
    {
        const _Float16* wp = wresA + (size_t)w * 24576 + lane * 8;
#pragma unroll
        for (int f = 0; f < 48; f++) wf[f] = *(const half8*)(wp + (size_t)f * 512);
    }
#pragma unroll
    for (int f = 0; f < 48; f++) asm volatile("" : "+a"(wf[f]));

    // ---- termination masks: stage words through wl (before wl is filled),
    //      then hold in 16 static registers per thread ----
    unsigned tmr0[4], tmr1[4], tmr2[4], tmr3[4];
    {
        unsigned* tw = (unsigned*)wl;
        if (tid < 64) {
            const int r = tid >> 2, word = tid & 3;
            unsigned m = 0;
            for (int b2 = 0; b2 < 32; b2++)
                m |= (term[(R0 + r) * 128 + word * 32 + b2] ? 1u : 0u) << b2;
            tw[tid] = m;
        }
        __syncthreads();
#pragma unroll
        for (int q = 0; q < 4; q++) {
            const int r4 = (kg * 4 + q) * 4;
            tmr0[q] = tw[r4 + 0];
            tmr1[q] = tw[r4 + 1];
            tmr2[q] = tw[r4 + 2];
            tmr3[q] = tw[r4 + 3];
        }
        __syncthreads();
    }

    // ---- stage LDS W tile (128KB linear, overwrites the term staging) ----
    for (int u = 0; u < 16; u++) {
        const int o = (u * 512 + tid) * 8;
        *(half8*)&wl[o] = *(const half8*)(wresL + o);
    }
    // ---- h0 -> hb buffer 0 (f32 -> f16, k8-major) ----
    {
        const int r = tid >> 5, c0 = (tid & 31) * 16;
        const float* gh = h0 + (size_t)(R0 + r) * 512 + c0;
        half8 v0, v1;
#pragma unroll
        for (int i = 0; i < 8; i++) { v0[i] = (_Float16)gh[i]; v1[i] = (_Float16)gh[8 + i]; }
        const int kb = c0 >> 3;
        *(half8*)&hb[kb * 128 + r * 8] = v0;
        *(half8*)&hb[(kb + 1) * 128 + r * 8] = v1;
    }
    __syncthreads();

    // hoisted addresses
    const int abase = kg * 128 + ln * 8;                 // a-frag LDS base (halfs)
    const _Float16* bl = &wl[(size_t)w * 8192];
    const _Float16* xbase = xps + (size_t)(bg * 128) * 8192 + tid * 16;
    _Float16* rp0 = rnn + (size_t)(R0 + kg * 4 + 0) * 128 * 512 + w * 16 + ln;
    _Float16* rp1 = rp0 + (size_t)128 * 512;
    _Float16* rp2 = rp1 + (size_t)128 * 512;
    _Float16* rp3 = rp2 + (size_t)128 * 512;

    half8 xc0 = *(const half8*)(xbase);        // xp(t=0)
    half8 xc1 = *(const half8*)(xbase + 8);
    unsigned tmask[4];

#pragma unroll 1
    for (int t = 0; t < 128; ++t) {
        if ((t & 31) == 0) {
            const int sel = t >> 5;
#pragma unroll
            for (int q = 0; q < 4; q++)
                tmask[q] = sel == 0 ? tmr0[q] : sel == 1 ? tmr1[q] : sel == 2 ? tmr2[q] : tmr3[q];
        }
        // prefetch xp(t+1) — a full step of latency cover
        const int tn = (t < 127) ? (t + 1) : 127;
        const _Float16* xnp = xbase + (size_t)tn * 8192;
        const half8 xn0 = *(const half8*)(xnp);
        const half8 xn1 = *(const half8*)(xnp + 8);

        const _Float16* hr = hb + (t & 1) * 8192;      // read buffer: h(t)
        _Float16* hw = hb + ((t & 1) ^ 1) * 8192;      // write buffer: h(t+1)

        f32x4 acc[4];
#pragma unroll
        for (int n = 0; n < 4; n++) acc[n] = (f32x4)0.0f;

#pragma unroll
        for (int s = 0; s < 16; s++) {
            const half8 a = *(const half8*)&hr[abase + s * 512];
            acc[0] = __builtin_amdgcn_mfma_f32_16x16x32_f16(a, wf[s],      acc[0], 0, 0, 0);
            acc[1] = __builtin_amdgcn_mfma_f32_16x16x32_f16(a, wf[16 + s], acc[1], 0, 0, 0);
            acc[2] = __builtin_amdgcn_mfma_f32_16x16x32_f16(a, wf[32 + s], acc[2], 0, 0, 0);
            const half8 b4 = *(const half8*)(bl + s * 512 + lane * 8);
            acc[3] = __builtin_amdgcn_mfma_f32_16x16x32_f16(a, b4, acc[3], 0, 0, 0);
        }

        // tanh; masked h(t+1) -> hw (other buffer: safe without barrier)
        _Float16 hh[16];
#pragma unroll
        for (int q = 0; q < 4; q++) {
            const bool dead = (tmask[q] >> (t & 31)) & 1;
#pragma unroll
            for (int nt = 0; nt < 4; nt++) {
                const int u = q * 4 + nt;
                const float xval = (float)(u < 8 ? xc0[u] : xc1[u - 8]);
                const float pre = acc[nt][q] + xval;
                const float e = __expf(2.0f * pre);
                const float hn = 1.0f - 2.0f * __builtin_amdgcn_rcpf(e + 1.0f);
                hh[q * 4 + nt] = (_Float16)hn;
                const int c = (nt * 8 + w) * 16 + ln;
                hw[(c >> 3) * 128 + (kg * 4 + q) * 8 + (c & 7)] =
                    dead ? (_Float16)0.0f : hh[q * 4 + nt];
            }
        }
        __syncthreads();   // the ONLY barrier: h(t+1) complete, h(t) reads done

        // rnn_out stores after barrier: drain overlaps next step's MFMA phase
        rp0[0] = hh[0]; rp0[128] = hh[1]; rp0[256] = hh[2]; rp0[384] = hh[3];
        rp1[0] = hh[4]; rp1[128] = hh[5]; rp1[256] = hh[6]; rp1[384] = hh[7];
        rp2[0] = hh[8]; rp2[128] = hh[9]; rp2[256] = hh[10]; rp2[384] = hh[11];
        rp3[0] = hh[12]; rp3[128] = hh[13]; rp3[256] = hh[14]; rp3[384] = hh[15];
        rp0 += 512; rp1 += 512; rp2 += 512; rp3 += 512;

        xc0 = xn0; xc1 = xn1;
    }

    // ---- h_final (masked h(128), lives in buffer 0) -> f32 at d_out + 65536*256 ----
    {
        const int r = tid >> 5, c0 = (tid & 31) * 16;
        const int kb = c0 >> 3;
        half8 v0 = *(const half8*)&hb[kb * 128 + r * 8];
        half8 v1 = *(const half8*)&hb[(kb + 1) * 128 + r * 8];
        float* gf = dout + (size_t)65536 * 256 + (size_t)(R0 + r) * 512 + c0;
#pragma unroll
        for (int i = 0; i < 8; i++) { gf[i] = (float)v0[i]; gf[8 + i] = (float)v1[i]; }
    }
}

// ---------------------------------------------------------------------------
// K3: logits[65536,256] (f32) = rnn_out(f16, in d_out) @ fc_w^T + fc_b
// ---------------------------------------------------------------------------
__global__ __launch_bounds__(512) void gemm_logits(const _Float16* Arnn,
                                                   const _Float16* __restrict__ Bw,
                                                   const float* __restrict__ biasv,
                                                   float* out) {
    __shared__ _Float16 As[128 * 32];
    __shared__ _Float16 Bs[256 * 32];
    const int tid = threadIdx.x;
    const int m0 = blockIdx.x * 128;
    const int lane = tid & 63, w = tid >> 6;
    const int wr = (w >> 2) * 64, wc = (w & 3) * 64;
    const int ln = lane & 15, kg = lane >> 4;

    f32x4 acc[4][4];
#pragma unroll
    for (int m = 0; m < 4; m++)
#pragma unroll
        for (int n = 0; n < 4; n++) acc[m][n] = (f32x4)0.0f;

    const int ar = tid >> 2, ac = (tid & 3) * 8;
    const int br = tid >> 1, bc = (tid & 1) * 16;

    for (int k0 = 0; k0 < 512; k0 += 32) {
        *(half8*)&As[ar * 32 + ac] = *(const half8*)(Arnn + (size_t)(m0 + ar) * 512 + k0 + ac);
        {
            const _Float16* gb = Bw + (size_t)br * 512 + k0 + bc;
            *(half8*)&Bs[br * 32 + bc] = *(const half8*)(gb);
            *(half8*)&Bs[br * 32 + bc + 8] = *(const half8*)(gb + 8);
        }
        __syncthreads();
        half8 af[4], bf[4];
#pragma unroll
        for (int m = 0; m < 4; m++) af[m] = *(const half8*)&As[(wr + m * 16 + ln) * 32 + kg * 8];
#pragma unroll
        for (int n = 0; n < 4; n++) bf[n] = *(const half8*)&Bs[(wc + n * 16 + ln) * 32 + kg * 8];
#pragma unroll
        for (int m = 0; m < 4; m++)
#pragma unroll
            for (int n = 0; n < 4; n++)
                acc[m][n] = __builtin_amdgcn_mfma_f32_16x16x32_f16(af[m], bf[n], acc[m][n], 0, 0, 0);
        __syncthreads();
    }
#pragma unroll
    for (int m = 0; m < 4; m++)
#pragma unroll
        for (int n = 0; n < 4; n++) {
            const int col = wc + n * 16 + ln;
            const float bv = biasv[col];
#pragma unroll
            for (int q = 0; q < 4; q++) {
                const int row = m0 + wr + m * 16 + kg * 4 + q;
                out[(size_t)row * 256 + col] = acc[m][n][q] + bv;
            }
        }
}

// ---------------------------------------------------------------------------
extern "C" void kernel_launch(void* const* d_in, const int* in_sizes, int n_in,
                              void* d_out, int out_size, void* d_ws, size_t ws_size,
                              hipStream_t stream) {
    const float* states = (const float*)d_in[0];
    const int*   term   = (const int*)d_in[1];
    const float* h0     = (const float*)d_in[2];
    const float* Wih    = (const float*)d_in[3];
    const float* Whh    = (const float*)d_in[4];
    const float* bih    = (const float*)d_in[5];
    const float* bhh    = (const float*)d_in[6];
    const float* fcw    = (const float*)d_in[7];
    const float* fcb    = (const float*)d_in[8];

    char* ws = (char*)d_ws;
    _Float16* xpw   = (_Float16*)(ws + XPW_OFF);
    _Float16* wih_h = (_Float16*)(ws + WIH_OFF);
    _Float16* fcw_h = (_Float16*)(ws + FCW_OFF);
    float*    bias2 = (float*)(ws + BIAS_OFF);
    _Float16* wresA = (_Float16*)(ws + WRESA_OFF);
    _Float16* wresL = (_Float16*)(ws + WRESL_OFF);

    conv_w<<<1024, 256, 0, stream>>>(Wih, Whh, fcw, bih, bhh, wih_h, fcw_h, bias2, wresA, wresL);
    gemm_xproj<<<4096, 256, 0, stream>>>(states, wih_h, bias2, xpw);
    rnn_scan12<<<32, 512, 0, stream>>>(xpw, wresA, wresL, term, h0, (float*)d_out);
    gemm_logits<<<512, 512, 0, stream>>>((const _Float16*)d_out, fcw_h, fcb, (float*)d_out);
}